// Round 2
// baseline (13893.953 us; speedup 1.0000x reference)
//
#include <hip/hip_runtime.h>
#include <hip/hip_cooperative_groups.h>
#include <math.h>

namespace cg = cooperative_groups;

#define NG 256        // grid blocks (== CUs)
#define NT 512        // threads per block
#define XSS 516       // LDS x stride (2-way bank alias only)
#define NLOGW 250     // logits wgs (32 vocab rows each)

// ---------------------------------------------------------------------------
// Vv[b,t,a] = sum_d enc[b,t,d] * attn_V[a,d]   (one-time precompute)
// grid: 16 b * 40 t-chunks (15 t each) = 640 wgs
// ---------------------------------------------------------------------------
__global__ __launch_bounds__(256) void k_vv(const float* __restrict__ enc,
                                            const float* __restrict__ attn_V,
                                            float* __restrict__ Vv) {
    int wg = blockIdx.x;
    int b = wg / 40, t0 = (wg % 40) * 15;
    int tid = threadIdx.x;
    __shared__ __align__(16) float encL[15][512];
    for (int i = tid; i < 15 * 512; i += 256) {
        int tl = i >> 9, d = i & 511;
        encL[tl][d] = enc[((size_t)(b * 600) + (t0 + tl)) * 512 + d];
    }
    __syncthreads();
    for (int half = 0; half < 2; ++half) {
        int a = tid + half * 256;
        const float4* wrow = reinterpret_cast<const float4*>(attn_V + (size_t)a * 512);
        float acc[15];
#pragma unroll
        for (int tl = 0; tl < 15; ++tl) acc[tl] = 0.f;
        for (int k = 0; k < 128; ++k) {
            float4 w = wrow[k];
#pragma unroll
            for (int tl = 0; tl < 15; ++tl) {
                float4 x = reinterpret_cast<const float4*>(&encL[tl][0])[k];
                acc[tl] += w.x * x.x + w.y * x.y + w.z * x.z + w.w * x.w;
            }
        }
        for (int tl = 0; tl < 15; ++tl)
            Vv[((size_t)(b * 600) + (t0 + tl)) * 512 + a] = acc[tl];
    }
}

// ---------------------------------------------------------------------------
// Persistent cooperative kernel: all 64 decode steps.
// ---------------------------------------------------------------------------
__global__ __launch_bounds__(NT, 1) void mega(
    const float* __restrict__ enc, const float* __restrict__ emb,
    const float* __restrict__ w_ih, const float* __restrict__ w_hh,
    const float* __restrict__ b_ih, const float* __restrict__ b_hh,
    const float* __restrict__ conv_w, const float* __restrict__ conv_b,
    const float* __restrict__ attn_W, const float* __restrict__ attn_fc_w,
    const float* __restrict__ attn_fc_b, const float* __restrict__ attn_b,
    const float* __restrict__ fc_w, const float* __restrict__ fc_b,
    const float* __restrict__ Vv,
    float* hbuf, float* ctxg, float* awg, float* scoreg, float* wqg,
    float* part, float* logZ, float* dout)
{
    cg::grid_group grid = cg::this_grid();
    const int g = blockIdx.x;
    const int tid = threadIdx.x;

    __shared__ float xs[16 * XSS];   // 33 KB staging (x / h / consts / pb / outL)
    __shared__ float aux[2600];      // pg[4*512] | tokf@2048 | wred@2064/2080 | red16/accL@0

    // ---- init: zero hbuf(16384) || ctx(8192) || aw(9600), contiguous ----
    for (int i = g * NT + tid; i < 34176; i += NG * NT) hbuf[i] = 0.f;
    grid.sync();

    for (int s = 0; s < 64; ++s) {
        const int p = s & 1;
        // ================= phase1: token finalize + GRU =================
        if (g < 128) {
            float* pg = aux;            // [4][512]
            float* tokf = aux + 2048;   // [16]
            if (s == 0) {
                if (tid < 16) tokf[tid] = 1.0f;   // SOS
                __syncthreads();
            } else {
                const int wv = tid >> 6, lane = tid & 63;
                for (int b = wv; b < 16; b += 8) {
                    float M = -3.4e38f, S = 0.f, I = 0.f;
                    for (int q = 0; q < 4; ++q) {
                        int pw = lane + (q << 6);
                        if (pw < NLOGW) {
                            const float* r = part + ((size_t)pw * 16 + b) * 4;
                            float m = r[0], se = r[1], ii = r[2];
                            if (m > M)      { S = S * expf(M - m) + se; M = m; I = ii; }
                            else if (m == M){ S += se; if (ii < I) I = ii; }
                            else            { S += se * expf(m - M); }
                        }
                    }
                    for (int off = 32; off; off >>= 1) {
                        float m  = __shfl_xor(M, off, 64);
                        float se = __shfl_xor(S, off, 64);
                        float ii = __shfl_xor(I, off, 64);
                        if (m > M)      { S = S * expf(M - m) + se; M = m; I = ii; }
                        else if (m == M){ S += se; if (ii < I) I = ii; }
                        else            { S += se * expf(m - M); }
                    }
                    if (lane == 0) {
                        tokf[b] = I;
                        if (g == 0) logZ[(s - 1) * 16 + b] = M + logf(S);
                    }
                }
                __syncthreads();
            }
            // GRU: wg g owns h-indices i = 4g..4g+3 for all 16 b.
            const int b  = tid & 15;
            const int u  = tid >> 4;        // [0,32)
            const int il = u & 3;
            const int pr = u >> 2;          // [0,8) -> 64-float k-slice
            const int i  = (g << 2) + il;
            float ar = 0.f, az = 0.f, axn = 0.f, ahn = 0.f;
            for (int pass = 0; pass < 3; ++pass) {
                for (int idx = tid; idx < 8192; idx += NT) {
                    int bb = idx >> 9, k = idx & 511;
                    float v;
                    if (pass == 0)      v = emb[(size_t)((int)tokf[bb]) * 512 + k];
                    else if (pass == 1) v = ctxg[(bb << 9) + k];
                    else                v = hbuf[((p << 4) + bb) * 512 + k];
                    xs[bb * XSS + k] = v;
                }
                __syncthreads();
                const float* wbase = (pass == 2) ? w_hh : w_ih;
                const size_t rl = (pass == 2) ? 512 : 1024;
                const int ko = (pass == 1) ? 512 : 0;
                const float4* wr = (const float4*)(wbase + (size_t)i * rl + ko) + (pr << 4);
                const float4* wz = (const float4*)(wbase + (size_t)(512 + i) * rl + ko) + (pr << 4);
                const float4* wn = (const float4*)(wbase + (size_t)(1024 + i) * rl + ko) + (pr << 4);
                const float4* xv = (const float4*)(xs + b * XSS) + (pr << 4);
                float s0 = 0.f, s1 = 0.f, s2 = 0.f;
#pragma unroll 4
                for (int k = 0; k < 16; ++k) {
                    float4 x = xv[k];
                    float4 a = wr[k]; s0 += a.x*x.x + a.y*x.y + a.z*x.z + a.w*x.w;
                    float4 c = wz[k]; s1 += c.x*x.x + c.y*x.y + c.z*x.z + c.w*x.w;
                    float4 d = wn[k]; s2 += d.x*x.x + d.y*x.y + d.z*x.z + d.w*x.w;
                }
                ar += s0; az += s1;
                if (pass < 2) axn += s2; else ahn += s2;
                if (pass < 2) __syncthreads();
            }
            {
                int base = (((b << 2) + il) << 3) + pr;
                pg[base] = ar; pg[512 + base] = az;
                pg[1024 + base] = axn; pg[1536 + base] = ahn;
            }
            __syncthreads();
            if (tid < 64) {
                int bb = tid & 15, ill = tid >> 4;
                int ii = (g << 2) + ill;
                float sr = 0.f, sz2 = 0.f, sxn = 0.f, shn = 0.f;
                int bs = ((bb << 2) + ill) << 3;
                for (int q = 0; q < 8; ++q) {
                    sr  += pg[bs + q];        sz2 += pg[512 + bs + q];
                    sxn += pg[1024 + bs + q]; shn += pg[1536 + bs + q];
                }
                sr  += b_ih[ii] + b_hh[ii];
                sz2 += b_ih[512 + ii] + b_hh[512 + ii];
                sxn += b_ih[1024 + ii];
                shn += b_hh[1024 + ii];
                float r = 1.f / (1.f + expf(-sr));
                float z = 1.f / (1.f + expf(-sz2));
                float n = tanhf(sxn + r * shn);
                float hp = xs[bb * XSS + ii];   // pass2 left h staged
                hbuf[(((p ^ 1) << 4) + bb) * 512 + ii] = (1.f - z) * n + z * hp;
            }
        }
        grid.sync();

        // ================= phase2: wq = h_new @ attn_W^T =================
        {
            const int b = g & 15, ac = g >> 4;
            for (int idx = tid; idx < 512; idx += NT)
                xs[idx] = hbuf[(((p ^ 1) << 4) + b) * 512 + idx];
            __syncthreads();
            const int al = tid >> 4, ln = tid & 15;
            const int a = (ac << 5) + al;
            const float4* wr = (const float4*)(attn_W + (size_t)a * 512) + (ln << 3);
            const float4* hv = (const float4*)xs + (ln << 3);
            float acc = 0.f;
#pragma unroll
            for (int k = 0; k < 8; ++k) {
                float4 w = wr[k], x = hv[k];
                acc += w.x*x.x + w.y*x.y + w.z*x.z + w.w*x.w;
            }
            for (int off = 8; off; off >>= 1) acc += __shfl_xor(acc, off, 64);
            if (ln == 0) wqg[(b << 9) + a] = acc;
        }
        grid.sync();

        // ================= phase3: scores =================
        {
            const int b = g & 15, tc = g >> 4;
            const int t0 = tc * 38;
            float* wqL  = xs;
            float* cw0  = xs + 512;
            float* cw1  = xs + 1024;
            float* cw2  = xs + 1536;
            float* cbab = xs + 2048;
            float* fcwL = xs + 2560;
            for (int a = tid; a < 512; a += NT) {
                wqL[a]  = wqg[(b << 9) + a];
                cw0[a]  = conv_w[a * 3];
                cw1[a]  = conv_w[a * 3 + 1];
                cw2[a]  = conv_w[a * 3 + 2];
                cbab[a] = conv_b[a] + attn_b[a];
                fcwL[a] = attn_fc_w[a];
            }
            __syncthreads();
            const float fcb = attn_fc_b[0];
            const int wv = tid >> 6, lane = tid & 63;
            for (int tl = wv; tl < 38; tl += 8) {
                const int t = t0 + tl;
                if (t < 600) {
                    const float awm = (t > 0)   ? awg[b * 600 + t - 1] : 0.f;
                    const float aw0 = awg[b * 600 + t];
                    const float awp = (t < 599) ? awg[b * 600 + t + 1] : 0.f;
                    const float* vv = Vv + ((size_t)b * 600 + t) * 512;
                    float acc = 0.f;
#pragma unroll
                    for (int q = 0; q < 8; ++q) {
                        const int a = lane + (q << 6);
                        float uu = wqL[a] + vv[a] + cbab[a]
                                 + cw0[a] * awm + cw1[a] * aw0 + cw2[a] * awp;
                        acc += tanhf(uu) * fcwL[a];
                    }
                    for (int off = 32; off; off >>= 1) acc += __shfl_xor(acc, off, 64);
                    if (lane == 0) scoreg[b * 600 + t] = acc + fcb;
                }
            }
        }
        grid.sync();

        // ================= phase4: softmax + ctx =================
        {
            const int b = g & 15, ec = g >> 4;
            float* pb    = xs;          // [600]
            float* wredM = aux + 2064;  // [8]
            float* wredS = aux + 2080;  // [8]
            float* red16 = aux;         // [16][32]
            float lm = -3.4e38f;
            for (int t = tid; t < 600; t += NT) {
                float v = scoreg[b * 600 + t];
                pb[t] = v;
                lm = fmaxf(lm, v);
            }
            for (int off = 32; off; off >>= 1) lm = fmaxf(lm, __shfl_xor(lm, off, 64));
            if ((tid & 63) == 0) wredM[tid >> 6] = lm;
            __syncthreads();
            float M = wredM[0];
#pragma unroll
            for (int q = 1; q < 8; ++q) M = fmaxf(M, wredM[q]);
            float lsum = 0.f;
            for (int t = tid; t < 600; t += NT) {
                float e = expf(pb[t] - M);
                pb[t] = e;
                lsum += e;
            }
            for (int off = 32; off; off >>= 1) lsum += __shfl_xor(lsum, off, 64);
            if ((tid & 63) == 0) wredS[tid >> 6] = lsum;
            __syncthreads();
            float S = 0.f;
#pragma unroll
            for (int q = 0; q < 8; ++q) S += wredS[q];
            const float invS = 1.f / S;
            if (ec == 0)
                for (int t = tid; t < 600; t += NT) awg[b * 600 + t] = pb[t] * invS;
            const int tg = tid >> 5, l32 = tid & 31;
            const int e = (ec << 5) + l32;
            float acc = 0.f;
            for (int t = tg; t < 600; t += 16)
                acc += pb[t] * enc[((size_t)b * 600 + t) * 512 + e];
            red16[(tg << 5) + l32] = acc;
            __syncthreads();
            if (tg == 0) {
                float a2 = 0.f;
#pragma unroll
                for (int q = 0; q < 16; ++q) a2 += red16[(q << 5) + l32];
                ctxg[(b << 9) + e] = a2 * invS;
            }
        }
        grid.sync();

        // ================= phase5: logits + partials =================
        {
            float* accL = aux;   // [16][16][4]
            float acc0 = 0.f, acc1 = 0.f;
            const int bb = tid & 15, jj = (tid >> 4) & 15;
            const int act = (tid < 256);
            const int v0 = (g << 5) + (jj << 1);
            for (int pass = 0; pass < 2; ++pass) {
                for (int idx = tid; idx < 8192; idx += NT) {
                    int b2 = idx >> 9, k = idx & 511;
                    xs[b2 * XSS + k] = pass ? ctxg[(b2 << 9) + k]
                                            : hbuf[(((p ^ 1) << 4) + b2) * 512 + k];
                }
                __syncthreads();
                if (g < NLOGW && act) {
                    const float4* w0 = (const float4*)(fc_w + (size_t)v0 * 1024 + (pass << 9));
                    const float4* w1 = (const float4*)(fc_w + (size_t)(v0 + 1) * 1024 + (pass << 9));
                    const float4* xv = (const float4*)(xs + bb * XSS);
#pragma unroll 4
                    for (int k = 0; k < 128; ++k) {
                        float4 x = xv[k];
                        float4 a = w0[k]; acc0 += a.x*x.x + a.y*x.y + a.z*x.z + a.w*x.w;
                        float4 c = w1[k]; acc1 += c.x*x.x + c.y*x.y + c.z*x.z + c.w*x.w;
                    }
                }
                __syncthreads();
            }
            if (g < NLOGW && act) {
                acc0 += fc_b[v0]; acc1 += fc_b[v0 + 1];
                float* o = dout + ((size_t)bb * 64 + s) * 8000;
                o[v0] = acc0; o[v0 + 1] = acc1;
                float bv, bi;
                if (acc0 >= acc1) { bv = acc0; bi = (float)v0; }
                else              { bv = acc1; bi = (float)(v0 + 1); }
                float se = expf(acc0 - bv) + expf(acc1 - bv);
                int rbase = (((bb << 4) + jj) << 2);
                accL[rbase] = bv; accL[rbase + 1] = bi; accL[rbase + 2] = se;
            }
            __syncthreads();
            if (g < NLOGW && tid < 16) {
                float M = -3.4e38f, I = 0.f, S = 0.f;
                for (int q = 0; q < 16; ++q) {
                    int rb = (((tid << 4) + q) << 2);
                    float m = accL[rb], ii = accL[rb + 1], se = accL[rb + 2];
                    if (m > M)      { S = S * expf(M - m) + se; M = m; I = ii; }
                    else if (m == M){ S += se; if (ii < I) I = ii; }
                    else            { S += se * expf(m - M); }
                }
                float* pr2 = part + ((size_t)g * 16 + tid) * 4;
                pr2[0] = M; pr2[1] = S; pr2[2] = I;
            }
        }
        grid.sync();
    }

    // ---- final logZ (s=63) ----
    if (g == 0) {
        const int wv = tid >> 6, lane = tid & 63;
        for (int b = wv; b < 16; b += 8) {
            float M = -3.4e38f, S = 0.f;
            for (int q = 0; q < 4; ++q) {
                int pw = lane + (q << 6);
                if (pw < NLOGW) {
                    const float* r = part + ((size_t)pw * 16 + b) * 4;
                    float m = r[0], se = r[1];
                    if (m > M)      { S = S * expf(M - m) + se; M = m; }
                    else if (m == M){ S += se; }
                    else            { S += se * expf(m - M); }
                }
            }
            for (int off = 32; off; off >>= 1) {
                float m  = __shfl_xor(M, off, 64);
                float se = __shfl_xor(S, off, 64);
                if (m > M)      { S = S * expf(M - m) + se; M = m; }
                else if (m == M){ S += se; }
                else            { S += se * expf(m - M); }
            }
            if (lane == 0) logZ[63 * 16 + b] = M + logf(S);
        }
    }
    grid.sync();
    // ---- normalize: logp = logits - logZ ----
    for (int i = g * NT + tid; i < 16 * 64 * 8000; i += NG * NT) {
        int bs = i / 8000;                        // b*64 + s
        dout[i] -= logZ[(bs & 63) * 16 + (bs >> 6)];
    }
}

// ---------------------------------------------------------------------------
extern "C" void kernel_launch(void* const* d_in, const int* in_sizes, int n_in,
                              void* d_out, int out_size, void* d_ws, size_t ws_size,
                              hipStream_t stream) {
    const float* enc       = (const float*)d_in[0];
    const float* emb       = (const float*)d_in[1];
    const float* w_ih      = (const float*)d_in[2];
    const float* w_hh      = (const float*)d_in[3];
    const float* b_ih      = (const float*)d_in[4];
    const float* b_hh      = (const float*)d_in[5];
    const float* conv_w    = (const float*)d_in[6];
    const float* conv_b    = (const float*)d_in[7];
    const float* attn_W    = (const float*)d_in[8];
    const float* attn_V    = (const float*)d_in[9];
    const float* attn_fc_w = (const float*)d_in[10];
    const float* attn_fc_b = (const float*)d_in[11];
    const float* attn_b    = (const float*)d_in[12];
    const float* fc_w      = (const float*)d_in[13];
    const float* fc_b      = (const float*)d_in[14];

    float* ws    = (float*)d_ws;
    float* Vv    = ws;                       // 16*600*512 = 4,915,200
    float* hbuf  = Vv + 4915200;             // 2*16*512 (then ctx, aw contiguous)
    float* ctx   = hbuf + 16384;             // 16*512
    float* aw    = ctx + 8192;               // 16*600
    float* score = aw + 9600;                // 16*600
    float* wq    = score + 9600;             // 16*512
    float* part  = wq + 8192;                // 250*16*4 (padded 16384)
    float* logZ  = part + 16384;             // 64*16
    float* dout  = (float*)d_out;

    k_vv<<<dim3(640), dim3(256), 0, stream>>>(enc, attn_V, Vv);

    void* args[] = {(void*)&enc, (void*)&emb, (void*)&w_ih, (void*)&w_hh,
                    (void*)&b_ih, (void*)&b_hh, (void*)&conv_w, (void*)&conv_b,
                    (void*)&attn_W, (void*)&attn_fc_w, (void*)&attn_fc_b,
                    (void*)&attn_b, (void*)&fc_w, (void*)&fc_b, (void*)&Vv,
                    (void*)&hbuf, (void*)&ctx, (void*)&aw, (void*)&score,
                    (void*)&wq, (void*)&part, (void*)&logZ, (void*)&dout};
    hipLaunchCooperativeKernel(reinterpret_cast<void*>(mega),
                               dim3(NG), dim3(NT), args, 0, stream);
}

// Round 3
// 10477.224 us; speedup vs baseline: 1.3261x; 1.3261x over previous
//
#include <hip/hip_runtime.h>
#include <math.h>

#define NG 256        // grid blocks (== CUs)
#define NT 512        // threads per block
#define XSS 516       // LDS x stride (2-way bank alias only)
#define NLOGW 250     // logits wgs (32 vocab rows each)

// ---------------------------------------------------------------------------
// Custom slotted grid barrier: unique slot per call site (zeroed pre-launch).
// Release fence -> arrival add (agent scope) -> tight spin -> acquire fence.
// ~3-5us vs ~33us for ROCm grid.sync (s_sleep backoff).
// ---------------------------------------------------------------------------
__device__ __forceinline__ void gbar(int* cnt, int slot, int tid) {
    __syncthreads();                 // drains each wave's vmcnt (stores in L2)
    if (tid == 0) {
        __threadfence();             // release: writeback L2 -> LLC
        __hip_atomic_fetch_add(cnt + slot, 1, __ATOMIC_RELAXED,
                               __HIP_MEMORY_SCOPE_AGENT);
        while (__hip_atomic_load(cnt + slot, __ATOMIC_RELAXED,
                                 __HIP_MEMORY_SCOPE_AGENT) < NG) {}
        __threadfence();             // acquire: invalidate stale L1/L2 lines
    }
    __syncthreads();
}

// ---------------------------------------------------------------------------
// Vv[b,t,a] = sum_d enc[b,t,d] * attn_V[a,d]   (one-time precompute)
// grid: 16 b * 40 t-chunks (15 t each) = 640 wgs
// ---------------------------------------------------------------------------
__global__ __launch_bounds__(256) void k_vv(const float* __restrict__ enc,
                                            const float* __restrict__ attn_V,
                                            float* __restrict__ Vv) {
    int wg = blockIdx.x;
    int b = wg / 40, t0 = (wg % 40) * 15;
    int tid = threadIdx.x;
    __shared__ __align__(16) float encL[15][512];
    for (int i = tid; i < 15 * 512; i += 256) {
        int tl = i >> 9, d = i & 511;
        encL[tl][d] = enc[((size_t)(b * 600) + (t0 + tl)) * 512 + d];
    }
    __syncthreads();
    for (int half = 0; half < 2; ++half) {
        int a = tid + half * 256;
        const float4* wrow = reinterpret_cast<const float4*>(attn_V + (size_t)a * 512);
        float acc[15];
#pragma unroll
        for (int tl = 0; tl < 15; ++tl) acc[tl] = 0.f;
        for (int k = 0; k < 128; ++k) {
            float4 w = wrow[k];
#pragma unroll
            for (int tl = 0; tl < 15; ++tl) {
                float4 x = reinterpret_cast<const float4*>(&encL[tl][0])[k];
                acc[tl] += w.x * x.x + w.y * x.y + w.z * x.z + w.w * x.w;
            }
        }
        for (int tl = 0; tl < 15; ++tl)
            Vv[((size_t)(b * 600) + (t0 + tl)) * 512 + a] = acc[tl];
    }
}

// ---------------------------------------------------------------------------
// Persistent cooperative kernel: all 64 decode steps.
// ---------------------------------------------------------------------------
__global__ __launch_bounds__(NT, 1) void mega(
    const float* __restrict__ enc, const float* __restrict__ emb,
    const float* __restrict__ w_ih, const float* __restrict__ w_hh,
    const float* __restrict__ b_ih, const float* __restrict__ b_hh,
    const float* __restrict__ conv_w, const float* __restrict__ conv_b,
    const float* __restrict__ attn_W, const float* __restrict__ attn_fc_w,
    const float* __restrict__ attn_fc_b, const float* __restrict__ attn_b,
    const float* __restrict__ fc_w, const float* __restrict__ fc_b,
    const float* __restrict__ Vv,
    float* hbuf, float* ctxg, float* awg, float* scoreg, float* wqg,
    float* part, float* logZ, int* cnt, float* dout)
{
    const int g = blockIdx.x;
    const int tid = threadIdx.x;
    int slot = 0;

    __shared__ float xs[16 * XSS];   // 33 KB staging (x / h / consts / pb / outL)
    __shared__ float aux[2600];      // pg[4*512] | tokf@2048 | wred@2064/2080 | red16/accL@0

    // hbuf/ctx/aw zeroed by hipMemsetAsync before launch.

    for (int s = 0; s < 64; ++s) {
        const int p = s & 1;
        // ================= phase1: token finalize + GRU =================
        if (g < 128) {
            float* pg = aux;            // [4][512]
            float* tokf = aux + 2048;   // [16]
            if (s == 0) {
                if (tid < 16) tokf[tid] = 1.0f;   // SOS
                __syncthreads();
            } else {
                const int wv = tid >> 6, lane = tid & 63;
                for (int b = wv; b < 16; b += 8) {
                    float M = -3.4e38f, S = 0.f, I = 0.f;
                    for (int q = 0; q < 4; ++q) {
                        int pw = lane + (q << 6);
                        if (pw < NLOGW) {
                            const float* r = part + ((size_t)pw * 16 + b) * 4;
                            float m = r[0], se = r[1], ii = r[2];
                            if (m > M)      { S = S * expf(M - m) + se; M = m; I = ii; }
                            else if (m == M){ S += se; if (ii < I) I = ii; }
                            else            { S += se * expf(m - M); }
                        }
                    }
                    for (int off = 32; off; off >>= 1) {
                        float m  = __shfl_xor(M, off, 64);
                        float se = __shfl_xor(S, off, 64);
                        float ii = __shfl_xor(I, off, 64);
                        if (m > M)      { S = S * expf(M - m) + se; M = m; I = ii; }
                        else if (m == M){ S += se; if (ii < I) I = ii; }
                        else            { S += se * expf(m - M); }
                    }
                    if (lane == 0) {
                        tokf[b] = I;
                        if (g == 0) logZ[(s - 1) * 16 + b] = M + logf(S);
                    }
                }
                __syncthreads();
            }
            // GRU: wg g owns h-indices i = 4g..4g+3 for all 16 b.
            const int b  = tid & 15;
            const int u  = tid >> 4;        // [0,32)
            const int il = u & 3;
            const int pr = u >> 2;          // [0,8) -> 64-float k-slice
            const int i  = (g << 2) + il;
            float ar = 0.f, az = 0.f, axn = 0.f, ahn = 0.f;
            for (int pass = 0; pass < 3; ++pass) {
                for (int idx = tid; idx < 8192; idx += NT) {
                    int bb = idx >> 9, k = idx & 511;
                    float v;
                    if (pass == 0)      v = emb[(size_t)((int)tokf[bb]) * 512 + k];
                    else if (pass == 1) v = ctxg[(bb << 9) + k];
                    else                v = hbuf[((p << 4) + bb) * 512 + k];
                    xs[bb * XSS + k] = v;
                }
                __syncthreads();
                const float* wbase = (pass == 2) ? w_hh : w_ih;
                const size_t rl = (pass == 2) ? 512 : 1024;
                const int ko = (pass == 1) ? 512 : 0;
                const float4* wr = (const float4*)(wbase + (size_t)i * rl + ko) + (pr << 4);
                const float4* wz = (const float4*)(wbase + (size_t)(512 + i) * rl + ko) + (pr << 4);
                const float4* wn = (const float4*)(wbase + (size_t)(1024 + i) * rl + ko) + (pr << 4);
                const float4* xv = (const float4*)(xs + b * XSS) + (pr << 4);
                float s0 = 0.f, s1 = 0.f, s2 = 0.f;
#pragma unroll 4
                for (int k = 0; k < 16; ++k) {
                    float4 x = xv[k];
                    float4 a = wr[k]; s0 += a.x*x.x + a.y*x.y + a.z*x.z + a.w*x.w;
                    float4 c = wz[k]; s1 += c.x*x.x + c.y*x.y + c.z*x.z + c.w*x.w;
                    float4 d = wn[k]; s2 += d.x*x.x + d.y*x.y + d.z*x.z + d.w*x.w;
                }
                ar += s0; az += s1;
                if (pass < 2) axn += s2; else ahn += s2;
                if (pass < 2) __syncthreads();
            }
            {
                int base = (((b << 2) + il) << 3) + pr;
                pg[base] = ar; pg[512 + base] = az;
                pg[1024 + base] = axn; pg[1536 + base] = ahn;
            }
            __syncthreads();
            if (tid < 64) {
                int bb = tid & 15, ill = tid >> 4;
                int ii = (g << 2) + ill;
                float sr = 0.f, sz2 = 0.f, sxn = 0.f, shn = 0.f;
                int bs = ((bb << 2) + ill) << 3;
                for (int q = 0; q < 8; ++q) {
                    sr  += pg[bs + q];        sz2 += pg[512 + bs + q];
                    sxn += pg[1024 + bs + q]; shn += pg[1536 + bs + q];
                }
                sr  += b_ih[ii] + b_hh[ii];
                sz2 += b_ih[512 + ii] + b_hh[512 + ii];
                sxn += b_ih[1024 + ii];
                shn += b_hh[1024 + ii];
                float r = 1.f / (1.f + expf(-sr));
                float z = 1.f / (1.f + expf(-sz2));
                float n = tanhf(sxn + r * shn);
                float hp = xs[bb * XSS + ii];   // pass2 left h staged
                hbuf[(((p ^ 1) << 4) + bb) * 512 + ii] = (1.f - z) * n + z * hp;
            }
        }
        gbar(cnt, slot++, tid);

        // ================= phase2: wq = h_new @ attn_W^T =================
        {
            const int b = g & 15, ac = g >> 4;
            for (int idx = tid; idx < 512; idx += NT)
                xs[idx] = hbuf[(((p ^ 1) << 4) + b) * 512 + idx];
            __syncthreads();
            const int al = tid >> 4, ln = tid & 15;
            const int a = (ac << 5) + al;
            const float4* wr = (const float4*)(attn_W + (size_t)a * 512) + (ln << 3);
            const float4* hv = (const float4*)xs + (ln << 3);
            float acc = 0.f;
#pragma unroll
            for (int k = 0; k < 8; ++k) {
                float4 w = wr[k], x = hv[k];
                acc += w.x*x.x + w.y*x.y + w.z*x.z + w.w*x.w;
            }
            for (int off = 8; off; off >>= 1) acc += __shfl_xor(acc, off, 64);
            if (ln == 0) wqg[(b << 9) + a] = acc;
        }
        gbar(cnt, slot++, tid);

        // ================= phase3: scores =================
        {
            const int b = g & 15, tc = g >> 4;
            const int t0 = tc * 38;
            float* wqL  = xs;
            float* cw0  = xs + 512;
            float* cw1  = xs + 1024;
            float* cw2  = xs + 1536;
            float* cbab = xs + 2048;
            float* fcwL = xs + 2560;
            for (int a = tid; a < 512; a += NT) {
                wqL[a]  = wqg[(b << 9) + a];
                cw0[a]  = conv_w[a * 3];
                cw1[a]  = conv_w[a * 3 + 1];
                cw2[a]  = conv_w[a * 3 + 2];
                cbab[a] = conv_b[a] + attn_b[a];
                fcwL[a] = attn_fc_w[a];
            }
            __syncthreads();
            const float fcb = attn_fc_b[0];
            const int wv = tid >> 6, lane = tid & 63;
            for (int tl = wv; tl < 38; tl += 8) {
                const int t = t0 + tl;
                if (t < 600) {
                    const float awm = (t > 0)   ? awg[b * 600 + t - 1] : 0.f;
                    const float aw0 = awg[b * 600 + t];
                    const float awp = (t < 599) ? awg[b * 600 + t + 1] : 0.f;
                    const float* vv = Vv + ((size_t)b * 600 + t) * 512;
                    float acc = 0.f;
#pragma unroll
                    for (int q = 0; q < 8; ++q) {
                        const int a = lane + (q << 6);
                        float uu = wqL[a] + vv[a] + cbab[a]
                                 + cw0[a] * awm + cw1[a] * aw0 + cw2[a] * awp;
                        acc += tanhf(uu) * fcwL[a];
                    }
                    for (int off = 32; off; off >>= 1) acc += __shfl_xor(acc, off, 64);
                    if (lane == 0) scoreg[b * 600 + t] = acc + fcb;
                }
            }
        }
        gbar(cnt, slot++, tid);

        // ================= phase4: softmax + ctx =================
        {
            const int b = g & 15, ec = g >> 4;
            float* pb    = xs;          // [600]
            float* wredM = aux + 2064;  // [8]
            float* wredS = aux + 2080;  // [8]
            float* red16 = aux;         // [16][32]
            float lm = -3.4e38f;
            for (int t = tid; t < 600; t += NT) {
                float v = scoreg[b * 600 + t];
                pb[t] = v;
                lm = fmaxf(lm, v);
            }
            for (int off = 32; off; off >>= 1) lm = fmaxf(lm, __shfl_xor(lm, off, 64));
            if ((tid & 63) == 0) wredM[tid >> 6] = lm;
            __syncthreads();
            float M = wredM[0];
#pragma unroll
            for (int q = 1; q < 8; ++q) M = fmaxf(M, wredM[q]);
            float lsum = 0.f;
            for (int t = tid; t < 600; t += NT) {
                float e = expf(pb[t] - M);
                pb[t] = e;
                lsum += e;
            }
            for (int off = 32; off; off >>= 1) lsum += __shfl_xor(lsum, off, 64);
            if ((tid & 63) == 0) wredS[tid >> 6] = lsum;
            __syncthreads();
            float S = 0.f;
#pragma unroll
            for (int q = 0; q < 8; ++q) S += wredS[q];
            const float invS = 1.f / S;
            if (ec == 0)
                for (int t = tid; t < 600; t += NT) awg[b * 600 + t] = pb[t] * invS;
            const int tg = tid >> 5, l32 = tid & 31;
            const int e = (ec << 5) + l32;
            float acc = 0.f;
            for (int t = tg; t < 600; t += 16)
                acc += pb[t] * enc[((size_t)b * 600 + t) * 512 + e];
            red16[(tg << 5) + l32] = acc;
            __syncthreads();
            if (tg == 0) {
                float a2 = 0.f;
#pragma unroll
                for (int q = 0; q < 16; ++q) a2 += red16[(q << 5) + l32];
                ctxg[(b << 9) + e] = a2 * invS;
            }
        }
        gbar(cnt, slot++, tid);

        // ================= phase5: logits + partials =================
        {
            float* accL = aux;   // [16][16][4]
            float acc0 = 0.f, acc1 = 0.f;
            const int bb = tid & 15, jj = (tid >> 4) & 15;
            const int act = (tid < 256);
            const int v0 = (g << 5) + (jj << 1);
            for (int pass = 0; pass < 2; ++pass) {
                for (int idx = tid; idx < 8192; idx += NT) {
                    int b2 = idx >> 9, k = idx & 511;
                    xs[b2 * XSS + k] = pass ? ctxg[(b2 << 9) + k]
                                            : hbuf[(((p ^ 1) << 4) + b2) * 512 + k];
                }
                __syncthreads();
                if (g < NLOGW && act) {
                    const float4* w0 = (const float4*)(fc_w + (size_t)v0 * 1024 + (pass << 9));
                    const float4* w1 = (const float4*)(fc_w + (size_t)(v0 + 1) * 1024 + (pass << 9));
                    const float4* xv = (const float4*)(xs + bb * XSS);
#pragma unroll 4
                    for (int k = 0; k < 128; ++k) {
                        float4 x = xv[k];
                        float4 a = w0[k]; acc0 += a.x*x.x + a.y*x.y + a.z*x.z + a.w*x.w;
                        float4 c = w1[k]; acc1 += c.x*x.x + c.y*x.y + c.z*x.z + c.w*x.w;
                    }
                }
                __syncthreads();
            }
            if (g < NLOGW && act) {
                acc0 += fc_b[v0]; acc1 += fc_b[v0 + 1];
                float* o = dout + ((size_t)bb * 64 + s) * 8000;
                o[v0] = acc0; o[v0 + 1] = acc1;
                float bv, bi;
                if (acc0 >= acc1) { bv = acc0; bi = (float)v0; }
                else              { bv = acc1; bi = (float)(v0 + 1); }
                float se = expf(acc0 - bv) + expf(acc1 - bv);
                int rbase = (((bb << 4) + jj) << 2);
                accL[rbase] = bv; accL[rbase + 1] = bi; accL[rbase + 2] = se;
            }
            __syncthreads();
            if (g < NLOGW && tid < 16) {
                float M = -3.4e38f, I = 0.f, S = 0.f;
                for (int q = 0; q < 16; ++q) {
                    int rb = (((tid << 4) + q) << 2);
                    float m = accL[rb], ii = accL[rb + 1], se = accL[rb + 2];
                    if (m > M)      { S = S * expf(M - m) + se; M = m; I = ii; }
                    else if (m == M){ S += se; if (ii < I) I = ii; }
                    else            { S += se * expf(m - M); }
                }
                float* pr2 = part + ((size_t)g * 16 + tid) * 4;
                pr2[0] = M; pr2[1] = S; pr2[2] = I;
            }
        }
        gbar(cnt, slot++, tid);
    }

    // ---- final logZ (s=63) ----
    if (g == 0) {
        const int wv = tid >> 6, lane = tid & 63;
        for (int b = wv; b < 16; b += 8) {
            float M = -3.4e38f, S = 0.f;
            for (int q = 0; q < 4; ++q) {
                int pw = lane + (q << 6);
                if (pw < NLOGW) {
                    const float* r = part + ((size_t)pw * 16 + b) * 4;
                    float m = r[0], se = r[1];
                    if (m > M)      { S = S * expf(M - m) + se; M = m; }
                    else if (m == M){ S += se; }
                    else            { S += se * expf(m - M); }
                }
            }
            for (int off = 32; off; off >>= 1) {
                float m  = __shfl_xor(M, off, 64);
                float se = __shfl_xor(S, off, 64);
                if (m > M)      { S = S * expf(M - m) + se; M = m; }
                else if (m == M){ S += se; }
                else            { S += se * expf(m - M); }
            }
            if (lane == 0) logZ[63 * 16 + b] = M + logf(S);
        }
    }
    gbar(cnt, slot++, tid);
    // ---- normalize: logp = logits - logZ ----
    for (int r = g; r < 1024; r += NG) {          // r = b*64 + s
        float z = logZ[(r & 63) * 16 + (r >> 6)];
        float* o = dout + (size_t)r * 8000;
        for (int i = tid; i < 8000; i += NT) o[i] -= z;
    }
}

// ---------------------------------------------------------------------------
extern "C" void kernel_launch(void* const* d_in, const int* in_sizes, int n_in,
                              void* d_out, int out_size, void* d_ws, size_t ws_size,
                              hipStream_t stream) {
    const float* enc       = (const float*)d_in[0];
    const float* emb       = (const float*)d_in[1];
    const float* w_ih      = (const float*)d_in[2];
    const float* w_hh      = (const float*)d_in[3];
    const float* b_ih      = (const float*)d_in[4];
    const float* b_hh      = (const float*)d_in[5];
    const float* conv_w    = (const float*)d_in[6];
    const float* conv_b    = (const float*)d_in[7];
    const float* attn_W    = (const float*)d_in[8];
    const float* attn_V    = (const float*)d_in[9];
    const float* attn_fc_w = (const float*)d_in[10];
    const float* attn_fc_b = (const float*)d_in[11];
    const float* attn_b    = (const float*)d_in[12];
    const float* fc_w      = (const float*)d_in[13];
    const float* fc_b      = (const float*)d_in[14];

    float* ws    = (float*)d_ws;
    float* Vv    = ws;                       // 16*600*512 = 4,915,200
    float* hbuf  = Vv + 4915200;             // 2*16*512
    float* ctx   = hbuf + 16384;             // 16*512
    float* aw    = ctx + 8192;               // 16*600
    float* score = aw + 9600;                // 16*600
    float* wq    = score + 9600;             // 16*512
    float* part  = wq + 8192;                // 250*16*4 (padded 16384)
    float* logZ  = part + 16384;             // 64*16 (padded 1024)
    int*   cnt   = (int*)(logZ + 1024);      // 512 barrier slots
    float* dout  = (float*)d_out;

    // zero hbuf(16384)+ctx(8192)+aw(9600) and the barrier slots (graph-legal)
    hipMemsetAsync(hbuf, 0, 34176 * sizeof(float), stream);
    hipMemsetAsync(cnt, 0, 512 * sizeof(int), stream);

    k_vv<<<dim3(640), dim3(256), 0, stream>>>(enc, attn_V, Vv);

    void* args[] = {(void*)&enc, (void*)&emb, (void*)&w_ih, (void*)&w_hh,
                    (void*)&b_ih, (void*)&b_hh, (void*)&conv_w, (void*)&conv_b,
                    (void*)&attn_W, (void*)&attn_fc_w, (void*)&attn_fc_b,
                    (void*)&attn_b, (void*)&fc_w, (void*)&fc_b, (void*)&Vv,
                    (void*)&hbuf, (void*)&ctx, (void*)&aw, (void*)&score,
                    (void*)&wq, (void*)&part, (void*)&logZ, (void*)&cnt,
                    (void*)&dout};
    hipLaunchCooperativeKernel(reinterpret_cast<void*>(mega),
                               dim3(NG), dim3(NT), args, 0, stream);
}

// Round 4
// 7262.952 us; speedup vs baseline: 1.9130x; 1.4426x over previous
//
#include <hip/hip_runtime.h>
#include <math.h>

#define NG 256        // grid blocks (== CUs)
#define NT 512        // threads per block
#define XSS 516       // LDS x stride (2-way bank alias only)
#define NLOGW 250     // logits wgs (32 vocab rows each)

// ---------------------------------------------------------------------------
// Epoch grid barrier, tree arrival + throttled broadcast spin.
// Layout in cnt (zeroed pre-launch): c0[16] at 32-int stride (128B lines),
// c1 at +512, go at +576. Counters are monotone (epoch-based, no reset).
// Release = vmcnt drain + buffer_wbl2 (writeback, no inv) via ATOMIC_RELEASE.
// Acquire = single buffer_inv via ATOMIC_ACQUIRE load on exit.
// ---------------------------------------------------------------------------
__device__ __forceinline__ void gbar(int* cnt, int epoch, int g, int tid) {
    __syncthreads();                 // all waves drain vmcnt before s_barrier
    if (tid == 0) {
        int* c0 = cnt + ((g & 15) << 5);
        int* c1 = cnt + 512;
        int* go = cnt + 576;
        int r = __hip_atomic_fetch_add(c0, 1, __ATOMIC_RELEASE,
                                       __HIP_MEMORY_SCOPE_AGENT);
        if (r == (epoch << 4) - 1) {             // 16th arriver of this group
            int r2 = __hip_atomic_fetch_add(c1, 1, __ATOMIC_RELAXED,
                                            __HIP_MEMORY_SCOPE_AGENT);
            if (r2 == (epoch << 4) - 1)          // 16th group done
                __hip_atomic_store(go, epoch, __ATOMIC_RELAXED,
                                   __HIP_MEMORY_SCOPE_AGENT);
        }
        int it = 0;
        while (__hip_atomic_load(go, __ATOMIC_RELAXED,
                                 __HIP_MEMORY_SCOPE_AGENT) < epoch) {
            if (++it > 2) __builtin_amdgcn_s_sleep(16);
        }
        (void)__hip_atomic_load(go, __ATOMIC_ACQUIRE,
                                __HIP_MEMORY_SCOPE_AGENT);   // buffer_inv
    }
    __syncthreads();
}

// ---------------------------------------------------------------------------
// Vv[b,t,a] = sum_d enc[b,t,d] * attn_V[a,d]   (one-time precompute)
// grid: 16 b * 40 t-chunks (15 t each) = 640 wgs
// ---------------------------------------------------------------------------
__global__ __launch_bounds__(256) void k_vv(const float* __restrict__ enc,
                                            const float* __restrict__ attn_V,
                                            float* __restrict__ Vv) {
    int wg = blockIdx.x;
    int b = wg / 40, t0 = (wg % 40) * 15;
    int tid = threadIdx.x;
    __shared__ __align__(16) float encL[15][512];
    for (int i = tid; i < 15 * 512; i += 256) {
        int tl = i >> 9, d = i & 511;
        encL[tl][d] = enc[((size_t)(b * 600) + (t0 + tl)) * 512 + d];
    }
    __syncthreads();
    for (int half = 0; half < 2; ++half) {
        int a = tid + half * 256;
        const float4* wrow = reinterpret_cast<const float4*>(attn_V + (size_t)a * 512);
        float acc[15];
#pragma unroll
        for (int tl = 0; tl < 15; ++tl) acc[tl] = 0.f;
        for (int k = 0; k < 128; ++k) {
            float4 w = wrow[k];
#pragma unroll
            for (int tl = 0; tl < 15; ++tl) {
                float4 x = reinterpret_cast<const float4*>(&encL[tl][0])[k];
                acc[tl] += w.x * x.x + w.y * x.y + w.z * x.z + w.w * x.w;
            }
        }
        for (int tl = 0; tl < 15; ++tl)
            Vv[((size_t)(b * 600) + (t0 + tl)) * 512 + a] = acc[tl];
    }
}

// ---------------------------------------------------------------------------
// Persistent kernel: all 64 decode steps.
// ---------------------------------------------------------------------------
__global__ __launch_bounds__(NT, 1) void mega(
    const float* __restrict__ enc, const float* __restrict__ emb,
    const float* __restrict__ w_ih, const float* __restrict__ w_hh,
    const float* __restrict__ b_ih, const float* __restrict__ b_hh,
    const float* __restrict__ conv_w, const float* __restrict__ conv_b,
    const float* __restrict__ attn_W, const float* __restrict__ attn_fc_w,
    const float* __restrict__ attn_fc_b, const float* __restrict__ attn_b,
    const float* __restrict__ fc_w, const float* __restrict__ fc_b,
    const float* __restrict__ Vv,
    float* hbuf, float* ctxg, float* awg, float* scoreg, float* wqg,
    float* part, float* logZ, int* cnt, float* dout)
{
    const int g = blockIdx.x;
    const int tid = threadIdx.x;
    int epoch = 0;

    __shared__ float xs[16 * XSS];   // 33 KB staging (x / h / consts / pb / outL)
    __shared__ float aux[2600];      // pg[4*512] | tokf@2048 | wred@2064/2080 | red16/accL@0

    // hbuf/ctx/aw zeroed by hipMemsetAsync before launch.

    for (int s = 0; s < 64; ++s) {
        const int p = s & 1;
        // ================= phase1: token finalize + GRU =================
        if (g < 128) {
            float* pg = aux;            // [4][512]
            float* tokf = aux + 2048;   // [16]
            if (s == 0) {
                if (tid < 16) tokf[tid] = 1.0f;   // SOS
                __syncthreads();
            } else {
                const int wv = tid >> 6, lane = tid & 63;
                for (int b = wv; b < 16; b += 8) {
                    float M = -3.4e38f, S = 0.f, I = 0.f;
                    for (int q = 0; q < 4; ++q) {
                        int pw = lane + (q << 6);
                        if (pw < NLOGW) {
                            const float* r = part + ((size_t)pw * 16 + b) * 4;
                            float m = r[0], se = r[1], ii = r[2];
                            if (m > M)      { S = S * expf(M - m) + se; M = m; I = ii; }
                            else if (m == M){ S += se; if (ii < I) I = ii; }
                            else            { S += se * expf(m - M); }
                        }
                    }
                    for (int off = 32; off; off >>= 1) {
                        float m  = __shfl_xor(M, off, 64);
                        float se = __shfl_xor(S, off, 64);
                        float ii = __shfl_xor(I, off, 64);
                        if (m > M)      { S = S * expf(M - m) + se; M = m; I = ii; }
                        else if (m == M){ S += se; if (ii < I) I = ii; }
                        else            { S += se * expf(m - M); }
                    }
                    if (lane == 0) {
                        tokf[b] = I;
                        if (g == 0) logZ[(s - 1) * 16 + b] = M + logf(S);
                    }
                }
                __syncthreads();
            }
            // GRU: wg g owns h-indices i = 4g..4g+3 for all 16 b.
            const int b  = tid & 15;
            const int u  = tid >> 4;        // [0,32)
            const int il = u & 3;
            const int pr = u >> 2;          // [0,8) -> 64-float k-slice
            const int i  = (g << 2) + il;
            float ar = 0.f, az = 0.f, axn = 0.f, ahn = 0.f;
            for (int pass = 0; pass < 3; ++pass) {
                for (int idx = tid; idx < 8192; idx += NT) {
                    int bb = idx >> 9, k = idx & 511;
                    float v;
                    if (pass == 0)      v = emb[(size_t)((int)tokf[bb]) * 512 + k];
                    else if (pass == 1) v = ctxg[(bb << 9) + k];
                    else                v = hbuf[((p << 4) + bb) * 512 + k];
                    xs[bb * XSS + k] = v;
                }
                __syncthreads();
                const float* wbase = (pass == 2) ? w_hh : w_ih;
                const size_t rl = (pass == 2) ? 512 : 1024;
                const int ko = (pass == 1) ? 512 : 0;
                const float4* wr = (const float4*)(wbase + (size_t)i * rl + ko) + (pr << 4);
                const float4* wz = (const float4*)(wbase + (size_t)(512 + i) * rl + ko) + (pr << 4);
                const float4* wn = (const float4*)(wbase + (size_t)(1024 + i) * rl + ko) + (pr << 4);
                const float4* xv = (const float4*)(xs + b * XSS) + (pr << 4);
                float s0 = 0.f, s1 = 0.f, s2 = 0.f;
#pragma unroll 4
                for (int k = 0; k < 16; ++k) {
                    float4 x = xv[k];
                    float4 a = wr[k]; s0 += a.x*x.x + a.y*x.y + a.z*x.z + a.w*x.w;
                    float4 c = wz[k]; s1 += c.x*x.x + c.y*x.y + c.z*x.z + c.w*x.w;
                    float4 d = wn[k]; s2 += d.x*x.x + d.y*x.y + d.z*x.z + d.w*x.w;
                }
                ar += s0; az += s1;
                if (pass < 2) axn += s2; else ahn += s2;
                if (pass < 2) __syncthreads();
            }
            {
                int base = (((b << 2) + il) << 3) + pr;
                pg[base] = ar; pg[512 + base] = az;
                pg[1024 + base] = axn; pg[1536 + base] = ahn;
            }
            __syncthreads();
            if (tid < 64) {
                int bb = tid & 15, ill = tid >> 4;
                int ii = (g << 2) + ill;
                float sr = 0.f, sz2 = 0.f, sxn = 0.f, shn = 0.f;
                int bs = ((bb << 2) + ill) << 3;
                for (int q = 0; q < 8; ++q) {
                    sr  += pg[bs + q];        sz2 += pg[512 + bs + q];
                    sxn += pg[1024 + bs + q]; shn += pg[1536 + bs + q];
                }
                sr  += b_ih[ii] + b_hh[ii];
                sz2 += b_ih[512 + ii] + b_hh[512 + ii];
                sxn += b_ih[1024 + ii];
                shn += b_hh[1024 + ii];
                float r = 1.f / (1.f + expf(-sr));
                float z = 1.f / (1.f + expf(-sz2));
                float n = tanhf(sxn + r * shn);
                float hp = xs[bb * XSS + ii];   // pass2 left h staged
                hbuf[(((p ^ 1) << 4) + bb) * 512 + ii] = (1.f - z) * n + z * hp;
            }
        }
        gbar(cnt, ++epoch, g, tid);

        // ================= phase2: wq = h_new @ attn_W^T =================
        {
            const int b = g & 15, ac = g >> 4;
            for (int idx = tid; idx < 512; idx += NT)
                xs[idx] = hbuf[(((p ^ 1) << 4) + b) * 512 + idx];
            __syncthreads();
            const int al = tid >> 4, ln = tid & 15;
            const int a = (ac << 5) + al;
            const float4* wr = (const float4*)(attn_W + (size_t)a * 512) + (ln << 3);
            const float4* hv = (const float4*)xs + (ln << 3);
            float acc = 0.f;
#pragma unroll
            for (int k = 0; k < 8; ++k) {
                float4 w = wr[k], x = hv[k];
                acc += w.x*x.x + w.y*x.y + w.z*x.z + w.w*x.w;
            }
            for (int off = 8; off; off >>= 1) acc += __shfl_xor(acc, off, 64);
            if (ln == 0) wqg[(b << 9) + a] = acc;
        }
        gbar(cnt, ++epoch, g, tid);

        // ================= phase3: scores =================
        {
            const int b = g & 15, tc = g >> 4;
            const int t0 = tc * 38;
            float* wqL  = xs;
            float* cw0  = xs + 512;
            float* cw1  = xs + 1024;
            float* cw2  = xs + 1536;
            float* cbab = xs + 2048;
            float* fcwL = xs + 2560;
            for (int a = tid; a < 512; a += NT) {
                wqL[a]  = wqg[(b << 9) + a];
                cw0[a]  = conv_w[a * 3];
                cw1[a]  = conv_w[a * 3 + 1];
                cw2[a]  = conv_w[a * 3 + 2];
                cbab[a] = conv_b[a] + attn_b[a];
                fcwL[a] = attn_fc_w[a];
            }
            __syncthreads();
            const float fcb = attn_fc_b[0];
            const int wv = tid >> 6, lane = tid & 63;
            for (int tl = wv; tl < 38; tl += 8) {
                const int t = t0 + tl;
                if (t < 600) {
                    const float awm = (t > 0)   ? awg[b * 600 + t - 1] : 0.f;
                    const float aw0 = awg[b * 600 + t];
                    const float awp = (t < 599) ? awg[b * 600 + t + 1] : 0.f;
                    const float* vv = Vv + ((size_t)b * 600 + t) * 512;
                    float acc = 0.f;
#pragma unroll
                    for (int q = 0; q < 8; ++q) {
                        const int a = lane + (q << 6);
                        float uu = wqL[a] + vv[a] + cbab[a]
                                 + cw0[a] * awm + cw1[a] * aw0 + cw2[a] * awp;
                        acc += tanhf(uu) * fcwL[a];
                    }
                    for (int off = 32; off; off >>= 1) acc += __shfl_xor(acc, off, 64);
                    if (lane == 0) scoreg[b * 600 + t] = acc + fcb;
                }
            }
        }
        gbar(cnt, ++epoch, g, tid);

        // ================= phase4: softmax + ctx =================
        {
            const int b = g & 15, ec = g >> 4;
            float* pb    = xs;          // [600]
            float* wredM = aux + 2064;  // [8]
            float* wredS = aux + 2080;  // [8]
            float* red16 = aux;         // [16][32]
            float lm = -3.4e38f;
            for (int t = tid; t < 600; t += NT) {
                float v = scoreg[b * 600 + t];
                pb[t] = v;
                lm = fmaxf(lm, v);
            }
            for (int off = 32; off; off >>= 1) lm = fmaxf(lm, __shfl_xor(lm, off, 64));
            if ((tid & 63) == 0) wredM[tid >> 6] = lm;
            __syncthreads();
            float M = wredM[0];
#pragma unroll
            for (int q = 1; q < 8; ++q) M = fmaxf(M, wredM[q]);
            float lsum = 0.f;
            for (int t = tid; t < 600; t += NT) {
                float e = expf(pb[t] - M);
                pb[t] = e;
                lsum += e;
            }
            for (int off = 32; off; off >>= 1) lsum += __shfl_xor(lsum, off, 64);
            if ((tid & 63) == 0) wredS[tid >> 6] = lsum;
            __syncthreads();
            float S = 0.f;
#pragma unroll
            for (int q = 0; q < 8; ++q) S += wredS[q];
            const float invS = 1.f / S;
            if (ec == 0)
                for (int t = tid; t < 600; t += NT) awg[b * 600 + t] = pb[t] * invS;
            const int tg = tid >> 5, l32 = tid & 31;
            const int e = (ec << 5) + l32;
            float acc = 0.f;
            for (int t = tg; t < 600; t += 16)
                acc += pb[t] * enc[((size_t)b * 600 + t) * 512 + e];
            red16[(tg << 5) + l32] = acc;
            __syncthreads();
            if (tg == 0) {
                float a2 = 0.f;
#pragma unroll
                for (int q = 0; q < 16; ++q) a2 += red16[(q << 5) + l32];
                ctxg[(b << 9) + e] = a2 * invS;
            }
        }
        gbar(cnt, ++epoch, g, tid);

        // ================= phase5: logits + partials =================
        {
            float* accL = aux;   // [16][16][4]
            float acc0 = 0.f, acc1 = 0.f;
            const int bb = tid & 15, jj = (tid >> 4) & 15;
            const int act = (tid < 256);
            const int v0 = (g << 5) + (jj << 1);
            for (int pass = 0; pass < 2; ++pass) {
                for (int idx = tid; idx < 8192; idx += NT) {
                    int b2 = idx >> 9, k = idx & 511;
                    xs[b2 * XSS + k] = pass ? ctxg[(b2 << 9) + k]
                                            : hbuf[(((p ^ 1) << 4) + b2) * 512 + k];
                }
                __syncthreads();
                if (g < NLOGW && act) {
                    const float4* w0 = (const float4*)(fc_w + (size_t)v0 * 1024 + (pass << 9));
                    const float4* w1 = (const float4*)(fc_w + (size_t)(v0 + 1) * 1024 + (pass << 9));
                    const float4* xv = (const float4*)(xs + bb * XSS);
#pragma unroll 4
                    for (int k = 0; k < 128; ++k) {
                        float4 x = xv[k];
                        float4 a = w0[k]; acc0 += a.x*x.x + a.y*x.y + a.z*x.z + a.w*x.w;
                        float4 c = w1[k]; acc1 += c.x*x.x + c.y*x.y + c.z*x.z + c.w*x.w;
                    }
                }
                __syncthreads();
            }
            if (g < NLOGW && act) {
                acc0 += fc_b[v0]; acc1 += fc_b[v0 + 1];
                float* o = dout + ((size_t)bb * 64 + s) * 8000;
                o[v0] = acc0; o[v0 + 1] = acc1;
                float bv, bi;
                if (acc0 >= acc1) { bv = acc0; bi = (float)v0; }
                else              { bv = acc1; bi = (float)(v0 + 1); }
                float se = expf(acc0 - bv) + expf(acc1 - bv);
                int rbase = (((bb << 4) + jj) << 2);
                accL[rbase] = bv; accL[rbase + 1] = bi; accL[rbase + 2] = se;
            }
            __syncthreads();
            if (g < NLOGW && tid < 16) {
                float M = -3.4e38f, I = 0.f, S = 0.f;
                for (int q = 0; q < 16; ++q) {
                    int rb = (((tid << 4) + q) << 2);
                    float m = accL[rb], ii = accL[rb + 1], se = accL[rb + 2];
                    if (m > M)      { S = S * expf(M - m) + se; M = m; I = ii; }
                    else if (m == M){ S += se; if (ii < I) I = ii; }
                    else            { S += se * expf(m - M); }
                }
                float* pr2 = part + ((size_t)g * 16 + tid) * 4;
                pr2[0] = M; pr2[1] = S; pr2[2] = I;
            }
        }
        gbar(cnt, ++epoch, g, tid);
    }

    // ---- final logZ (s=63) ----
    if (g == 0) {
        const int wv = tid >> 6, lane = tid & 63;
        for (int b = wv; b < 16; b += 8) {
            float M = -3.4e38f, S = 0.f;
            for (int q = 0; q < 4; ++q) {
                int pw = lane + (q << 6);
                if (pw < NLOGW) {
                    const float* r = part + ((size_t)pw * 16 + b) * 4;
                    float m = r[0], se = r[1];
                    if (m > M)      { S = S * expf(M - m) + se; M = m; }
                    else if (m == M){ S += se; }
                    else            { S += se * expf(m - M); }
                }
            }
            for (int off = 32; off; off >>= 1) {
                float m  = __shfl_xor(M, off, 64);
                float se = __shfl_xor(S, off, 64);
                if (m > M)      { S = S * expf(M - m) + se; M = m; }
                else if (m == M){ S += se; }
                else            { S += se * expf(m - M); }
            }
            if (lane == 0) logZ[63 * 16 + b] = M + logf(S);
        }
    }
    gbar(cnt, ++epoch, g, tid);
    // ---- normalize: logp = logits - logZ ----
    for (int r = g; r < 1024; r += NG) {          // r = b*64 + s
        float z = logZ[(r & 63) * 16 + (r >> 6)];
        float* o = dout + (size_t)r * 8000;
        for (int i = tid; i < 8000; i += NT) o[i] -= z;
    }
}

// ---------------------------------------------------------------------------
extern "C" void kernel_launch(void* const* d_in, const int* in_sizes, int n_in,
                              void* d_out, int out_size, void* d_ws, size_t ws_size,
                              hipStream_t stream) {
    const float* enc       = (const float*)d_in[0];
    const float* emb       = (const float*)d_in[1];
    const float* w_ih      = (const float*)d_in[2];
    const float* w_hh      = (const float*)d_in[3];
    const float* b_ih      = (const float*)d_in[4];
    const float* b_hh      = (const float*)d_in[5];
    const float* conv_w    = (const float*)d_in[6];
    const float* conv_b    = (const float*)d_in[7];
    const float* attn_W    = (const float*)d_in[8];
    const float* attn_V    = (const float*)d_in[9];
    const float* attn_fc_w = (const float*)d_in[10];
    const float* attn_fc_b = (const float*)d_in[11];
    const float* attn_b    = (const float*)d_in[12];
    const float* fc_w      = (const float*)d_in[13];
    const float* fc_b      = (const float*)d_in[14];

    float* ws    = (float*)d_ws;
    float* Vv    = ws;                       // 16*600*512 = 4,915,200
    float* hbuf  = Vv + 4915200;             // 2*16*512
    float* ctx   = hbuf + 16384;             // 16*512
    float* aw    = ctx + 8192;               // 16*600
    float* score = aw + 9600;                // 16*600
    float* wq    = score + 9600;             // 16*512
    float* part  = wq + 8192;                // 250*16*4 (padded 16384)
    float* logZ  = part + 16384;             // 64*16 (padded 1024)
    int*   cnt   = (int*)(logZ + 1024);      // 1024 ints: c0[16 lines]+c1+go
    float* dout  = (float*)d_out;

    // zero hbuf(16384)+ctx(8192)+aw(9600) and barrier state (graph-legal)
    hipMemsetAsync(hbuf, 0, 34176 * sizeof(float), stream);
    hipMemsetAsync(cnt, 0, 1024 * sizeof(int), stream);

    k_vv<<<dim3(640), dim3(256), 0, stream>>>(enc, attn_V, Vv);

    void* args[] = {(void*)&enc, (void*)&emb, (void*)&w_ih, (void*)&w_hh,
                    (void*)&b_ih, (void*)&b_hh, (void*)&conv_w, (void*)&conv_b,
                    (void*)&attn_W, (void*)&attn_fc_w, (void*)&attn_fc_b,
                    (void*)&attn_b, (void*)&fc_w, (void*)&fc_b, (void*)&Vv,
                    (void*)&hbuf, (void*)&ctx, (void*)&aw, (void*)&score,
                    (void*)&wq, (void*)&part, (void*)&logZ, (void*)&cnt,
                    (void*)&dout};
    hipLaunchCooperativeKernel(reinterpret_cast<void*>(mega),
                               dim3(NG), dim3(NT), args, 0, stream);
}

// Round 5
// 6548.237 us; speedup vs baseline: 2.1218x; 1.1091x over previous
//
#include <hip/hip_runtime.h>
#include <math.h>

#define NG 256        // grid blocks (== CUs)
#define NT 512        // threads per block
#define XSS 516       // LDS x stride (2-way bank alias only)
#define NLOGW 250     // logits wgs (32 vocab rows each)

// ---------------------------------------------------------------------------
// LLC-direct (device-coherent) scalar access for MUTABLE buffers.
// Relaxed agent-scope atomics compile to global_load/store sc0 sc1: bypass L1
// and per-XCD L2, read/write the device coherence point. Read-only weights
// use normal cached loads and are NEVER invalidated (no fences anywhere).
// ---------------------------------------------------------------------------
__device__ __forceinline__ float ldc(const float* p) {
    return __hip_atomic_load(p, __ATOMIC_RELAXED, __HIP_MEMORY_SCOPE_AGENT);
}
__device__ __forceinline__ void stc(float* p, float v) {
    __hip_atomic_store(p, v, __ATOMIC_RELAXED, __HIP_MEMORY_SCOPE_AGENT);
}

// ---------------------------------------------------------------------------
// Fence-free epoch grid barrier (tree arrival + throttled spin).
// cnt layout (zeroed pre-launch): c0[16] at 32-int stride, c1 at +512,
// go at +576. Monotone epochs. Data coherence comes from sc1 accesses, so
// no release/acquire fences (no wbl2, no buffer_inv) are needed here.
// __syncthreads() before arrival drains vmcnt -> sc1 stores are LLC-visible.
// ---------------------------------------------------------------------------
__device__ __forceinline__ void gbar(int* cnt, int epoch, int g, int tid) {
    __syncthreads();
    if (tid == 0) {
        int* c0 = cnt + ((g & 15) << 5);
        int* c1 = cnt + 512;
        int* go = cnt + 576;
        int r = __hip_atomic_fetch_add(c0, 1, __ATOMIC_RELAXED,
                                       __HIP_MEMORY_SCOPE_AGENT);
        if (r == (epoch << 4) - 1) {             // 16th arriver of this group
            int r2 = __hip_atomic_fetch_add(c1, 1, __ATOMIC_RELAXED,
                                            __HIP_MEMORY_SCOPE_AGENT);
            if (r2 == (epoch << 4) - 1)          // 16th group done
                __hip_atomic_store(go, epoch, __ATOMIC_RELAXED,
                                   __HIP_MEMORY_SCOPE_AGENT);
        }
        int it = 0;
        while (__hip_atomic_load(go, __ATOMIC_RELAXED,
                                 __HIP_MEMORY_SCOPE_AGENT) < epoch) {
            if (++it > 4) __builtin_amdgcn_s_sleep(8);
        }
    }
    __syncthreads();
}

// ---------------------------------------------------------------------------
// Vv[b,t,a] = sum_d enc[b,t,d] * attn_V[a,d]   (one-time precompute)
// grid: 16 b * 40 t-chunks (15 t each) = 640 wgs
// ---------------------------------------------------------------------------
__global__ __launch_bounds__(256) void k_vv(const float* __restrict__ enc,
                                            const float* __restrict__ attn_V,
                                            float* __restrict__ Vv) {
    int wg = blockIdx.x;
    int b = wg / 40, t0 = (wg % 40) * 15;
    int tid = threadIdx.x;
    __shared__ __align__(16) float encL[15][512];
    for (int i = tid; i < 15 * 512; i += 256) {
        int tl = i >> 9, d = i & 511;
        encL[tl][d] = enc[((size_t)(b * 600) + (t0 + tl)) * 512 + d];
    }
    __syncthreads();
    for (int half = 0; half < 2; ++half) {
        int a = tid + half * 256;
        const float4* wrow = reinterpret_cast<const float4*>(attn_V + (size_t)a * 512);
        float acc[15];
#pragma unroll
        for (int tl = 0; tl < 15; ++tl) acc[tl] = 0.f;
        for (int k = 0; k < 128; ++k) {
            float4 w = wrow[k];
#pragma unroll
            for (int tl = 0; tl < 15; ++tl) {
                float4 x = reinterpret_cast<const float4*>(&encL[tl][0])[k];
                acc[tl] += w.x * x.x + w.y * x.y + w.z * x.z + w.w * x.w;
            }
        }
        for (int tl = 0; tl < 15; ++tl)
            Vv[((size_t)(b * 600) + (t0 + tl)) * 512 + a] = acc[tl];
    }
}

// ---------------------------------------------------------------------------
// Persistent kernel: all 64 decode steps.
// ---------------------------------------------------------------------------
__global__ __launch_bounds__(NT, 1) void mega(
    const float* __restrict__ enc, const float* __restrict__ emb,
    const float* __restrict__ w_ih, const float* __restrict__ w_hh,
    const float* __restrict__ b_ih, const float* __restrict__ b_hh,
    const float* __restrict__ conv_w, const float* __restrict__ conv_b,
    const float* __restrict__ attn_W, const float* __restrict__ attn_fc_w,
    const float* __restrict__ attn_fc_b, const float* __restrict__ attn_b,
    const float* __restrict__ fc_w, const float* __restrict__ fc_b,
    const float* __restrict__ Vv,
    float* hbuf, float* ctxg, float* awg, float* scoreg, float* wqg,
    float* part, float* logZ, int* cnt, float* dout)
{
    const int g = blockIdx.x;
    const int tid = threadIdx.x;
    int epoch = 0;

    __shared__ float xs[16 * XSS];   // 33 KB staging (x / h / consts / pb / outL)
    __shared__ float aux[2600];      // pg[4*512] | tokf@2048 | wred@2064/2080 | red16/accL@0

    // hbuf/ctx/aw zeroed by hipMemsetAsync before launch.

    for (int s = 0; s < 64; ++s) {
        const int p = s & 1;
        // ================= phase1: token finalize + GRU =================
        if (g < 128) {
            float* pg = aux;            // [4][512]
            float* tokf = aux + 2048;   // [16]
            if (s == 0) {
                if (tid < 16) tokf[tid] = 1.0f;   // SOS
                __syncthreads();
            } else {
                const int wv = tid >> 6, lane = tid & 63;
                for (int b = wv; b < 16; b += 8) {
                    float M = -3.4e38f, S = 0.f, I = 0.f;
                    for (int q = 0; q < 4; ++q) {
                        int pw = lane + (q << 6);
                        if (pw < NLOGW) {
                            const float* r = part + ((size_t)pw * 16 + b) * 4;
                            float m = ldc(r), se = ldc(r + 1), ii = ldc(r + 2);
                            if (m > M)      { S = S * expf(M - m) + se; M = m; I = ii; }
                            else if (m == M){ S += se; if (ii < I) I = ii; }
                            else            { S += se * expf(m - M); }
                        }
                    }
                    for (int off = 32; off; off >>= 1) {
                        float m  = __shfl_xor(M, off, 64);
                        float se = __shfl_xor(S, off, 64);
                        float ii = __shfl_xor(I, off, 64);
                        if (m > M)      { S = S * expf(M - m) + se; M = m; I = ii; }
                        else if (m == M){ S += se; if (ii < I) I = ii; }
                        else            { S += se * expf(m - M); }
                    }
                    if (lane == 0) {
                        tokf[b] = I;
                        if (g == 0) stc(&logZ[(s - 1) * 16 + b], M + logf(S));
                    }
                }
                __syncthreads();
            }
            // GRU: wg g owns h-indices i = 4g..4g+3 for all 16 b.
            const int b  = tid & 15;
            const int u  = tid >> 4;        // [0,32)
            const int il = u & 3;
            const int pr = u >> 2;          // [0,8) -> 64-float k-slice
            const int i  = (g << 2) + il;
            float ar = 0.f, az = 0.f, axn = 0.f, ahn = 0.f;
            for (int pass = 0; pass < 3; ++pass) {
                for (int idx = tid; idx < 8192; idx += NT) {
                    int bb = idx >> 9, k = idx & 511;
                    float v;
                    if (pass == 0)      v = emb[(size_t)((int)tokf[bb]) * 512 + k];
                    else if (pass == 1) v = ldc(&ctxg[(bb << 9) + k]);
                    else                v = ldc(&hbuf[((p << 4) + bb) * 512 + k]);
                    xs[bb * XSS + k] = v;
                }
                __syncthreads();
                const float* wbase = (pass == 2) ? w_hh : w_ih;
                const size_t rl = (pass == 2) ? 512 : 1024;
                const int ko = (pass == 1) ? 512 : 0;
                const float4* wr = (const float4*)(wbase + (size_t)i * rl + ko) + (pr << 4);
                const float4* wz = (const float4*)(wbase + (size_t)(512 + i) * rl + ko) + (pr << 4);
                const float4* wn = (const float4*)(wbase + (size_t)(1024 + i) * rl + ko) + (pr << 4);
                const float4* xv = (const float4*)(xs + b * XSS) + (pr << 4);
                float s0 = 0.f, s1 = 0.f, s2 = 0.f;
#pragma unroll 4
                for (int k = 0; k < 16; ++k) {
                    float4 x = xv[k];
                    float4 a = wr[k]; s0 += a.x*x.x + a.y*x.y + a.z*x.z + a.w*x.w;
                    float4 c = wz[k]; s1 += c.x*x.x + c.y*x.y + c.z*x.z + c.w*x.w;
                    float4 d = wn[k]; s2 += d.x*x.x + d.y*x.y + d.z*x.z + d.w*x.w;
                }
                ar += s0; az += s1;
                if (pass < 2) axn += s2; else ahn += s2;
                if (pass < 2) __syncthreads();
            }
            {
                int base = (((b << 2) + il) << 3) + pr;
                pg[base] = ar; pg[512 + base] = az;
                pg[1024 + base] = axn; pg[1536 + base] = ahn;
            }
            __syncthreads();
            if (tid < 64) {
                int bb = tid & 15, ill = tid >> 4;
                int ii = (g << 2) + ill;
                float sr = 0.f, sz2 = 0.f, sxn = 0.f, shn = 0.f;
                int bs = ((bb << 2) + ill) << 3;
                for (int q = 0; q < 8; ++q) {
                    sr  += pg[bs + q];        sz2 += pg[512 + bs + q];
                    sxn += pg[1024 + bs + q]; shn += pg[1536 + bs + q];
                }
                sr  += b_ih[ii] + b_hh[ii];
                sz2 += b_ih[512 + ii] + b_hh[512 + ii];
                sxn += b_ih[1024 + ii];
                shn += b_hh[1024 + ii];
                float r = 1.f / (1.f + expf(-sr));
                float z = 1.f / (1.f + expf(-sz2));
                float n = tanhf(sxn + r * shn);
                float hp = xs[bb * XSS + ii];   // pass2 left h staged
                stc(&hbuf[(((p ^ 1) << 4) + bb) * 512 + ii], (1.f - z) * n + z * hp);
            }
        }
        gbar(cnt, ++epoch, g, tid);

        // ================= phase2: wq = h_new @ attn_W^T =================
        {
            const int b = g & 15, ac = g >> 4;
            for (int idx = tid; idx < 512; idx += NT)
                xs[idx] = ldc(&hbuf[(((p ^ 1) << 4) + b) * 512 + idx]);
            __syncthreads();
            const int al = tid >> 4, ln = tid & 15;
            const int a = (ac << 5) + al;
            const float4* wr = (const float4*)(attn_W + (size_t)a * 512) + (ln << 3);
            const float4* hv = (const float4*)xs + (ln << 3);
            float acc = 0.f;
#pragma unroll
            for (int k = 0; k < 8; ++k) {
                float4 w = wr[k], x = hv[k];
                acc += w.x*x.x + w.y*x.y + w.z*x.z + w.w*x.w;
            }
            for (int off = 8; off; off >>= 1) acc += __shfl_xor(acc, off, 64);
            if (ln == 0) stc(&wqg[(b << 9) + a], acc);
        }
        gbar(cnt, ++epoch, g, tid);

        // ================= phase3: scores =================
        {
            const int b = g & 15, tc = g >> 4;
            const int t0 = tc * 38;
            float* wqL  = xs;
            float* cw0  = xs + 512;
            float* cw1  = xs + 1024;
            float* cw2  = xs + 1536;
            float* cbab = xs + 2048;
            float* fcwL = xs + 2560;
            for (int a = tid; a < 512; a += NT) {
                wqL[a]  = ldc(&wqg[(b << 9) + a]);
                cw0[a]  = conv_w[a * 3];
                cw1[a]  = conv_w[a * 3 + 1];
                cw2[a]  = conv_w[a * 3 + 2];
                cbab[a] = conv_b[a] + attn_b[a];
                fcwL[a] = attn_fc_w[a];
            }
            __syncthreads();
            const float fcb = attn_fc_b[0];
            const int wv = tid >> 6, lane = tid & 63;
            for (int tl = wv; tl < 38; tl += 8) {
                const int t = t0 + tl;
                if (t < 600) {
                    const float awm = (t > 0)   ? ldc(&awg[b * 600 + t - 1]) : 0.f;
                    const float aw0 = ldc(&awg[b * 600 + t]);
                    const float awp = (t < 599) ? ldc(&awg[b * 600 + t + 1]) : 0.f;
                    const float* vv = Vv + ((size_t)b * 600 + t) * 512;
                    float acc = 0.f;
#pragma unroll
                    for (int q = 0; q < 8; ++q) {
                        const int a = lane + (q << 6);
                        float uu = wqL[a] + vv[a] + cbab[a]
                                 + cw0[a] * awm + cw1[a] * aw0 + cw2[a] * awp;
                        acc += tanhf(uu) * fcwL[a];
                    }
                    for (int off = 32; off; off >>= 1) acc += __shfl_xor(acc, off, 64);
                    if (lane == 0) stc(&scoreg[b * 600 + t], acc + fcb);
                }
            }
        }
        gbar(cnt, ++epoch, g, tid);

        // ================= phase4: softmax + ctx =================
        {
            const int b = g & 15, ec = g >> 4;
            float* pb    = xs;          // [600]
            float* wredM = aux + 2064;  // [8]
            float* wredS = aux + 2080;  // [8]
            float* red16 = aux;         // [16][32]
            float lm = -3.4e38f;
            for (int t = tid; t < 600; t += NT) {
                float v = ldc(&scoreg[b * 600 + t]);
                pb[t] = v;
                lm = fmaxf(lm, v);
            }
            for (int off = 32; off; off >>= 1) lm = fmaxf(lm, __shfl_xor(lm, off, 64));
            if ((tid & 63) == 0) wredM[tid >> 6] = lm;
            __syncthreads();
            float M = wredM[0];
#pragma unroll
            for (int q = 1; q < 8; ++q) M = fmaxf(M, wredM[q]);
            float lsum = 0.f;
            for (int t = tid; t < 600; t += NT) {
                float e = expf(pb[t] - M);
                pb[t] = e;
                lsum += e;
            }
            for (int off = 32; off; off >>= 1) lsum += __shfl_xor(lsum, off, 64);
            if ((tid & 63) == 0) wredS[tid >> 6] = lsum;
            __syncthreads();
            float S = 0.f;
#pragma unroll
            for (int q = 0; q < 8; ++q) S += wredS[q];
            const float invS = 1.f / S;
            if (ec == 0)
                for (int t = tid; t < 600; t += NT) stc(&awg[b * 600 + t], pb[t] * invS);
            const int tg = tid >> 5, l32 = tid & 31;
            const int e = (ec << 5) + l32;
            float acc = 0.f;
            for (int t = tg; t < 600; t += 16)
                acc += pb[t] * enc[((size_t)b * 600 + t) * 512 + e];
            red16[(tg << 5) + l32] = acc;
            __syncthreads();
            if (tg == 0) {
                float a2 = 0.f;
#pragma unroll
                for (int q = 0; q < 16; ++q) a2 += red16[(q << 5) + l32];
                stc(&ctxg[(b << 9) + e], a2 * invS);
            }
        }
        gbar(cnt, ++epoch, g, tid);

        // ================= phase5: logits + partials =================
        {
            float* accL = aux;   // [16][16][4]
            float acc0 = 0.f, acc1 = 0.f;
            const int bb = tid & 15, jj = (tid >> 4) & 15;
            const int act = (tid < 256);
            const int v0 = (g << 5) + (jj << 1);
            for (int pass = 0; pass < 2; ++pass) {
                for (int idx = tid; idx < 8192; idx += NT) {
                    int b2 = idx >> 9, k = idx & 511;
                    xs[b2 * XSS + k] = pass ? ldc(&ctxg[(b2 << 9) + k])
                                            : ldc(&hbuf[(((p ^ 1) << 4) + b2) * 512 + k]);
                }
                __syncthreads();
                if (g < NLOGW && act) {
                    const float4* w0 = (const float4*)(fc_w + (size_t)v0 * 1024 + (pass << 9));
                    const float4* w1 = (const float4*)(fc_w + (size_t)(v0 + 1) * 1024 + (pass << 9));
                    const float4* xv = (const float4*)(xs + bb * XSS);
#pragma unroll 4
                    for (int k = 0; k < 128; ++k) {
                        float4 x = xv[k];
                        float4 a = w0[k]; acc0 += a.x*x.x + a.y*x.y + a.z*x.z + a.w*x.w;
                        float4 c = w1[k]; acc1 += c.x*x.x + c.y*x.y + c.z*x.z + c.w*x.w;
                    }
                }
                __syncthreads();
            }
            if (g < NLOGW && act) {
                acc0 += fc_b[v0]; acc1 += fc_b[v0 + 1];
                float* o = dout + ((size_t)bb * 64 + s) * 8000;
                stc(o + v0, acc0);
                stc(o + v0 + 1, acc1);
                float bv, bi;
                if (acc0 >= acc1) { bv = acc0; bi = (float)v0; }
                else              { bv = acc1; bi = (float)(v0 + 1); }
                float se = expf(acc0 - bv) + expf(acc1 - bv);
                int rbase = (((bb << 4) + jj) << 2);
                accL[rbase] = bv; accL[rbase + 1] = bi; accL[rbase + 2] = se;
            }
            __syncthreads();
            if (g < NLOGW && tid < 16) {
                float M = -3.4e38f, I = 0.f, S = 0.f;
                for (int q = 0; q < 16; ++q) {
                    int rb = (((tid << 4) + q) << 2);
                    float m = accL[rb], ii = accL[rb + 1], se = accL[rb + 2];
                    if (m > M)      { S = S * expf(M - m) + se; M = m; I = ii; }
                    else if (m == M){ S += se; if (ii < I) I = ii; }
                    else            { S += se * expf(m - M); }
                }
                float* pr2 = part + ((size_t)g * 16 + tid) * 4;
                stc(pr2, M); stc(pr2 + 1, S); stc(pr2 + 2, I);
            }
        }
        gbar(cnt, ++epoch, g, tid);
    }

    // ---- final logZ (s=63) ----
    if (g == 0) {
        const int wv = tid >> 6, lane = tid & 63;
        for (int b = wv; b < 16; b += 8) {
            float M = -3.4e38f, S = 0.f;
            for (int q = 0; q < 4; ++q) {
                int pw = lane + (q << 6);
                if (pw < NLOGW) {
                    const float* r = part + ((size_t)pw * 16 + b) * 4;
                    float m = ldc(r), se = ldc(r + 1);
                    if (m > M)      { S = S * expf(M - m) + se; M = m; }
                    else if (m == M){ S += se; }
                    else            { S += se * expf(m - M); }
                }
            }
            for (int off = 32; off; off >>= 1) {
                float m  = __shfl_xor(M, off, 64);
                float se = __shfl_xor(S, off, 64);
                if (m > M)      { S = S * expf(M - m) + se; M = m; }
                else if (m == M){ S += se; }
                else            { S += se * expf(m - M); }
            }
            if (lane == 0) stc(&logZ[63 * 16 + b], M + logf(S));
        }
    }
    gbar(cnt, ++epoch, g, tid);
    // ---- normalize: logp = logits - logZ ----
    // dout lines were only ever written via sc1 (write-through): any L2 fill
    // below reads LLC-fresh data; normal cached ops are safe here.
    for (int r = g; r < 1024; r += NG) {          // r = b*64 + s
        float z = ldc(&logZ[(r & 63) * 16 + (r >> 6)]);
        float* o = dout + (size_t)r * 8000;
        for (int i = tid; i < 8000; i += NT) o[i] -= z;
    }
}

// ---------------------------------------------------------------------------
extern "C" void kernel_launch(void* const* d_in, const int* in_sizes, int n_in,
                              void* d_out, int out_size, void* d_ws, size_t ws_size,
                              hipStream_t stream) {
    const float* enc       = (const float*)d_in[0];
    const float* emb       = (const float*)d_in[1];
    const float* w_ih      = (const float*)d_in[2];
    const float* w_hh      = (const float*)d_in[3];
    const float* b_ih      = (const float*)d_in[4];
    const float* b_hh      = (const float*)d_in[5];
    const float* conv_w    = (const float*)d_in[6];
    const float* conv_b    = (const float*)d_in[7];
    const float* attn_W    = (const float*)d_in[8];
    const float* attn_V    = (const float*)d_in[9];
    const float* attn_fc_w = (const float*)d_in[10];
    const float* attn_fc_b = (const float*)d_in[11];
    const float* attn_b    = (const float*)d_in[12];
    const float* fc_w      = (const float*)d_in[13];
    const float* fc_b      = (const float*)d_in[14];

    float* ws    = (float*)d_ws;
    float* Vv    = ws;                       // 16*600*512 = 4,915,200
    float* hbuf  = Vv + 4915200;             // 2*16*512
    float* ctx   = hbuf + 16384;             // 16*512
    float* aw    = ctx + 8192;               // 16*600
    float* score = aw + 9600;                // 16*600
    float* wq    = score + 9600;             // 16*512
    float* part  = wq + 8192;                // 250*16*4 (padded 16384)
    float* logZ  = part + 16384;             // 64*16 (padded 1024)
    int*   cnt   = (int*)(logZ + 1024);      // 1024 ints: c0[16 lines]+c1+go
    float* dout  = (float*)d_out;

    // zero hbuf(16384)+ctx(8192)+aw(9600) and barrier state (graph-legal)
    hipMemsetAsync(hbuf, 0, 34176 * sizeof(float), stream);
    hipMemsetAsync(cnt, 0, 1024 * sizeof(int), stream);

    k_vv<<<dim3(640), dim3(256), 0, stream>>>(enc, attn_V, Vv);

    void* args[] = {(void*)&enc, (void*)&emb, (void*)&w_ih, (void*)&w_hh,
                    (void*)&b_ih, (void*)&b_hh, (void*)&conv_w, (void*)&conv_b,
                    (void*)&attn_W, (void*)&attn_fc_w, (void*)&attn_fc_b,
                    (void*)&attn_b, (void*)&fc_w, (void*)&fc_b, (void*)&Vv,
                    (void*)&hbuf, (void*)&ctx, (void*)&aw, (void*)&score,
                    (void*)&wq, (void*)&part, (void*)&logZ, (void*)&cnt,
                    (void*)&dout};
    hipLaunchCooperativeKernel(reinterpret_cast<void*>(mega),
                               dim3(NG), dim3(NT), args, 0, stream);
}